// Round 1
// baseline (183.143 us; speedup 1.0000x reference)
//
#include <hip/hip_runtime.h>

#define DHEAD 128

// ---------------- Kernel 1: fused QKV projection ----------------
// out[j] = b[j] + sum_d x[d] * W[d*D + j]; 16 rows per block amortizes the
// 3*64KB weight stream (512 blocks -> ~100MB L2 traffic total).
__global__ __launch_bounds__(128) void qkv_kernel(
    const float* __restrict__ x,
    const float* __restrict__ Wq, const float* __restrict__ bq,
    const float* __restrict__ Wk, const float* __restrict__ bk,
    const float* __restrict__ Wv, const float* __restrict__ bv,
    float* __restrict__ q, float* __restrict__ k, float* __restrict__ v)
{
    const int ROWS = 16;
    int j = threadIdx.x;                 // 0..127 output dim
    int row0 = blockIdx.x * ROWS;
    __shared__ float xs[ROWS][DHEAD];
    #pragma unroll
    for (int r = 0; r < ROWS; ++r)
        xs[r][j] = x[(size_t)(row0 + r) * DHEAD + j];
    __syncthreads();

    float aq[ROWS], ak[ROWS], av[ROWS];
    float bqv = bq[j], bkv = bk[j], bvv = bv[j];
    #pragma unroll
    for (int r = 0; r < ROWS; ++r) { aq[r] = bqv; ak[r] = bkv; av[r] = bvv; }

    for (int d = 0; d < DHEAD; ++d) {
        float wq = Wq[d * DHEAD + j];
        float wk = Wk[d * DHEAD + j];
        float wv = Wv[d * DHEAD + j];
        #pragma unroll
        for (int r = 0; r < ROWS; ++r) {
            float xv = xs[r][d];
            aq[r] = fmaf(xv, wq, aq[r]);
            ak[r] = fmaf(xv, wk, ak[r]);
            av[r] = fmaf(xv, wv, av[r]);
        }
    }
    #pragma unroll
    for (int r = 0; r < ROWS; ++r) {
        size_t o = (size_t)(row0 + r) * DHEAD + j;
        q[o] = aq[r]; k[o] = ak[r]; v[o] = av[r];
    }
}

// ---------------- Kernel 2: sliding-window attention ----------------
// One wave (64 lanes) per query. Lane holds dims {2*lane, 2*lane+1}.
// Online softmax over the valid part of the +-half window.
__global__ __launch_bounds__(256) void attn_kernel(
    const float* __restrict__ q, const float* __restrict__ k,
    const float* __restrict__ v, float* __restrict__ out,
    const int* __restrict__ wsz, int B, int S)
{
    int gid  = blockIdx.x * (blockDim.x >> 6) + (threadIdx.x >> 6); // query id
    int lane = threadIdx.x & 63;
    if (gid >= B * S) return;
    int b = gid / S;
    int s = gid - b * S;
    int half = wsz[0] >> 1;

    const float scale = 0.08838834764831845f; // 1/sqrt(128)

    const float2* qp = (const float2*)(q + (size_t)gid * DHEAD);
    float2 qv = qp[lane];

    int start = s - half; if (start < 0) start = 0;
    int end   = s + half; if (end > S - 1) end = S - 1;

    const float2* kb = (const float2*)(k + (size_t)b * S * DHEAD);
    const float2* vb = (const float2*)(v + (size_t)b * S * DHEAD);

    float m = -1e30f, l = 0.0f;
    float2 acc = make_float2(0.0f, 0.0f);

    for (int idx = start; idx <= end; ++idx) {
        float2 kv = kb[(size_t)idx * (DHEAD / 2) + lane];
        float part = qv.x * kv.x + qv.y * kv.y;
        #pragma unroll
        for (int off = 32; off > 0; off >>= 1)
            part += __shfl_xor(part, off, 64);
        float sc = part * scale;

        float mn    = fmaxf(m, sc);
        float alpha = __expf(m - mn);
        float p     = __expf(sc - mn);

        float2 vv = vb[(size_t)idx * (DHEAD / 2) + lane];
        acc.x = acc.x * alpha + p * vv.x;
        acc.y = acc.y * alpha + p * vv.y;
        l = l * alpha + p;
        m = mn;
    }

    float inv = 1.0f / l;
    float2* op = (float2*)(out + (size_t)gid * DHEAD);
    op[lane] = make_float2(acc.x * inv, acc.y * inv);
}

extern "C" void kernel_launch(void* const* d_in, const int* in_sizes, int n_in,
                              void* d_out, int out_size, void* d_ws, size_t ws_size,
                              hipStream_t stream) {
    const float* x  = (const float*)d_in[0];
    const float* Wq = (const float*)d_in[1];
    const float* bq = (const float*)d_in[2];
    const float* Wk = (const float*)d_in[3];
    const float* bk = (const float*)d_in[4];
    const float* Wv = (const float*)d_in[5];
    const float* bv = (const float*)d_in[6];
    const int* wsz  = (const int*)d_in[7];

    const int B = 2, S = 4096;          // fixed by setup_inputs()
    const int N = B * S;                // 8192 rows

    float* q = (float*)d_ws;
    float* k = q + (size_t)N * DHEAD;
    float* v = k + (size_t)N * DHEAD;

    qkv_kernel<<<N / 16, 128, 0, stream>>>(x, Wq, bq, Wk, bk, Wv, bv, q, k, v);

    // one wave per query, 4 waves per block
    attn_kernel<<<N / 4, 256, 0, stream>>>(q, k, v, (float*)d_out, wsz, B, S);
}

// Round 2
// 100.414 us; speedup vs baseline: 1.8239x; 1.8239x over previous
//
#include <hip/hip_runtime.h>
#include <hip/hip_bf16.h>

typedef __attribute__((ext_vector_type(8))) short short8;
typedef __attribute__((ext_vector_type(4))) float f32x4;

union U16x8 { uint4 u; short8 s; unsigned short us[8]; };

#define S_LEN 4096
#define DH    128
#define TQ    32          // queries per attn block
#define KW    160         // key window per block (TQ + 128)
#define KSTR  136         // K LDS row stride (bf16 elems), 272B = 17*16 -> b128-aligned, 2-way banks
#define VSTR  138         // V LDS row stride: 69 dwords -> quad groups hit distinct banks (conflict-free u16 frag reads)
#define PSTR  168         // P LDS row stride, 336B = 21*16 -> b128-aligned

// ---------------- Kernel 1: QKV projection, fp32 math, bf16 output ----------
// 256 threads: j = t&127 (output dim), g = t>>7 selects row-half. 16 rows/block,
// grid 512 -> 2 blocks/CU, 16 waves/CU (vs old 4).
__global__ __launch_bounds__(256) void qkv_kernel(
    const float* __restrict__ x,
    const float* __restrict__ Wq, const float* __restrict__ bq,
    const float* __restrict__ Wk, const float* __restrict__ bk,
    const float* __restrict__ Wv, const float* __restrict__ bv,
    __hip_bfloat16* __restrict__ q, __hip_bfloat16* __restrict__ k,
    __hip_bfloat16* __restrict__ v)
{
    const int t = threadIdx.x;
    const int j = t & 127;
    const int g = t >> 7;            // 0/1 -> rows 8g..8g+7
    const int row0 = blockIdx.x * 16;

    __shared__ float xs[16][DH];
    for (int c = t; c < 512; c += 256) {           // 16*128 floats = 512 float4
        int r = c >> 5, f = c & 31;
        ((float4*)xs[r])[f] = ((const float4*)(x + (size_t)(row0 + r) * DH))[f];
    }
    __syncthreads();

    float aq[8], ak[8], av[8];
    const float bqv = bq[j], bkv = bk[j], bvv = bv[j];
    #pragma unroll
    for (int r = 0; r < 8; ++r) { aq[r] = bqv; ak[r] = bkv; av[r] = bvv; }

    #pragma unroll 2
    for (int d4 = 0; d4 < 32; ++d4) {
        float4 xv[8];
        #pragma unroll
        for (int r = 0; r < 8; ++r) xv[r] = *(const float4*)&xs[g*8 + r][d4*4];
        #pragma unroll
        for (int dd = 0; dd < 4; ++dd) {
            int d = d4*4 + dd;
            float wq = Wq[d*DH + j], wk = Wk[d*DH + j], wv = Wv[d*DH + j];
            #pragma unroll
            for (int r = 0; r < 8; ++r) {
                float xvs = (&xv[r].x)[dd];
                aq[r] = fmaf(xvs, wq, aq[r]);
                ak[r] = fmaf(xvs, wk, ak[r]);
                av[r] = fmaf(xvs, wv, av[r]);
            }
        }
    }
    #pragma unroll
    for (int r = 0; r < 8; ++r) {
        size_t o = (size_t)(row0 + g*8 + r) * DH + j;
        q[o] = __float2bfloat16(aq[r]);
        k[o] = __float2bfloat16(ak[r]);
        v[o] = __float2bfloat16(av[r]);
    }
}

// ---------------- Kernel 2: MFMA sliding-window attention -------------------
// Block = 4 waves, 32 queries. Waves (rb,cc): rb = 16-query row-block, cc = key/dim half.
// Phase A: S = Q K^T via mfma_16x16x32_bf16 (K-tile in LDS). fp32 masked softmax
// with cross-wave max/sum combine. P -> LDS bf16. Phase B: V restaged into same
// LDS buffer, O = P V via MFMA. Epilogue scales by 1/l.
__global__ __launch_bounds__(256) void attn_kernel(
    const __hip_bfloat16* __restrict__ qg,
    const __hip_bfloat16* __restrict__ kg,
    const __hip_bfloat16* __restrict__ vg,
    float* __restrict__ out, const int* __restrict__ wsz)
{
    __shared__ __align__(16) unsigned short KV[KW * VSTR];      // 22080 elems: K (stride 136) then V (stride 138)
    __shared__ __align__(16) __hip_bfloat16 Ps[2][16 * PSTR];
    __shared__ float pmax[2][2][16];
    __shared__ float psum[2][2][16];

    const int t    = threadIdx.x;
    const int qblk = blockIdx.x;            // 0..255
    const int b    = qblk >> 7;
    const int s0   = (qblk & 127) * TQ;
    const int k0   = s0 - 64;
    const int half = wsz[0] >> 1;

    const int wave = t >> 6, lane = t & 63;
    const int rb = wave >> 1, cc = wave & 1;
    const int i = lane & 15, g = lane >> 4;

    const __hip_bfloat16* kbase = kg + (size_t)b * S_LEN * DH;
    const __hip_bfloat16* vbase = vg + (size_t)b * S_LEN * DH;

    // ---- stage K tile (row-major, stride KSTR); OOB keys -> zeros ----
    for (int c = t; c < KW * 16; c += 256) {
        int row = c >> 4, cg = c & 15;
        int key = k0 + row;
        uint4 val = make_uint4(0u, 0u, 0u, 0u);
        if (key >= 0 && key < S_LEN)
            val = *(const uint4*)(kbase + (size_t)key * DH + cg*8);
        *(uint4*)&KV[row * KSTR + cg*8] = val;
    }

    // ---- Q A-fragments straight from global (row m = lane&15, k = quad*8+j) ----
    short8 aq[4];
    {
        const __hip_bfloat16* qrow = qg + (size_t)(b * S_LEN + s0 + rb*16 + i) * DH;
        #pragma unroll
        for (int kc = 0; kc < 4; ++kc) {
            U16x8 u; u.u = *(const uint4*)(qrow + kc*32 + g*8);
            aq[kc] = u.s;
        }
    }
    __syncthreads();

    // ---- scores: 5 key-tiles x 4 K-chunks ----
    f32x4 acc[5];
    #pragma unroll
    for (int kt = 0; kt < 5; ++kt) { acc[kt][0]=0.f; acc[kt][1]=0.f; acc[kt][2]=0.f; acc[kt][3]=0.f; }
    #pragma unroll
    for (int kt = 0; kt < 5; ++kt) {
        int col0 = cc*80 + kt*16;
        #pragma unroll
        for (int kc = 0; kc < 4; ++kc) {
            short8 bk = *(short8*)&KV[(col0 + i) * KSTR + kc*32 + g*8];
            acc[kt] = __builtin_amdgcn_mfma_f32_16x16x32_bf16(aq[kc], bk, acc[kt], 0, 0, 0);
        }
    }

    // ---- mask + per-wave row max (C layout: col = lane&15, row = quad*4+r) ----
    const float scale = 0.08838834764831845f;
    float sc[5][4], m4[4];
    #pragma unroll
    for (int r = 0; r < 4; ++r) m4[r] = -3e30f;
    #pragma unroll
    for (int kt = 0; kt < 5; ++kt) {
        int key = k0 + cc*80 + kt*16 + i;
        #pragma unroll
        for (int r = 0; r < 4; ++r) {
            int qrow = s0 + rb*16 + g*4 + r;
            bool valid = (key >= 0) && (key < S_LEN) && (key >= qrow - half) && (key <= qrow + half);
            float sv = valid ? acc[kt][r] * scale : -1e30f;
            sc[kt][r] = sv;
            m4[r] = fmaxf(m4[r], sv);
        }
    }
    #pragma unroll
    for (int r = 0; r < 4; ++r) {
        #pragma unroll
        for (int m = 1; m < 16; m <<= 1)
            m4[r] = fmaxf(m4[r], __shfl_xor(m4[r], m, 64));
    }
    if (i == 0) {
        #pragma unroll
        for (int r = 0; r < 4; ++r) pmax[rb][cc][g*4 + r] = m4[r];
    }
    __syncthreads();   // barrier1: all K reads done; pmax visible

    // ---- issue V global loads early (K LDS buffer gets reused for V) ----
    uint4 vstage[10];
    #pragma unroll
    for (int idx = 0; idx < 10; ++idx) {
        int c = t + idx*256;                    // < 2560
        int row = c >> 4, cg = c & 15;
        int key = k0 + row;
        uint4 val = make_uint4(0u, 0u, 0u, 0u);
        if (key >= 0 && key < S_LEN)
            val = *(const uint4*)(vbase + (size_t)key * DH + cg*8);
        vstage[idx] = val;
    }

    // ---- softmax (fp32), write P as bf16 ----
    float M[4], l4[4];
    #pragma unroll
    for (int r = 0; r < 4; ++r) {
        M[r] = fmaxf(m4[r], pmax[rb][cc ^ 1][g*4 + r]);
        l4[r] = 0.f;
    }
    #pragma unroll
    for (int kt = 0; kt < 5; ++kt) {
        #pragma unroll
        for (int r = 0; r < 4; ++r) {
            float p = __expf(sc[kt][r] - M[r]);
            l4[r] += p;
            Ps[rb][(g*4 + r) * PSTR + cc*80 + kt*16 + i] = __float2bfloat16(p);
        }
    }
    #pragma unroll
    for (int r = 0; r < 4; ++r) {
        #pragma unroll
        for (int m = 1; m < 16; m <<= 1)
            l4[r] += __shfl_xor(l4[r], m, 64);
    }
    if (i == 0) {
        #pragma unroll
        for (int r = 0; r < 4; ++r) psum[rb][cc][g*4 + r] = l4[r];
    }

    // ---- write V tile into LDS (stride VSTR, dword writes: byte 276*row+16*cg) ----
    #pragma unroll
    for (int idx = 0; idx < 10; ++idx) {
        int c = t + idx*256;
        int row = c >> 4, cg = c & 15;
        unsigned int* dst = (unsigned int*)((char*)KV + (size_t)(row * VSTR + cg*8) * 2);
        dst[0] = vstage[idx].x; dst[1] = vstage[idx].y;
        dst[2] = vstage[idx].z; dst[3] = vstage[idx].w;
    }
    __syncthreads();   // barrier2: P, psum, V all visible

    // ---- PV: A = P (16x160), B = V (160 x 128), wave covers 64 dims ----
    float linv[4];
    #pragma unroll
    for (int r = 0; r < 4; ++r)
        linv[r] = 1.0f / (psum[rb][0][g*4 + r] + psum[rb][1][g*4 + r]);

    short8 ap[5];
    #pragma unroll
    for (int kc = 0; kc < 5; ++kc)
        ap[kc] = *(short8*)&Ps[rb][i * PSTR + kc*32 + g*8];

    f32x4 oacc[4];
    #pragma unroll
    for (int nt = 0; nt < 4; ++nt) { oacc[nt][0]=0.f; oacc[nt][1]=0.f; oacc[nt][2]=0.f; oacc[nt][3]=0.f; }

    const unsigned short* Vu = KV;
    #pragma unroll
    for (int nt = 0; nt < 4; ++nt) {
        int n0 = cc*64 + nt*16;
        #pragma unroll
        for (int kc = 0; kc < 5; ++kc) {
            U16x8 bu;
            #pragma unroll
            for (int jj = 0; jj < 8; ++jj)
                bu.us[jj] = Vu[(kc*32 + g*8 + jj) * VSTR + n0 + i];
            oacc[nt] = __builtin_amdgcn_mfma_f32_16x16x32_bf16(ap[kc], bu.s, oacc[nt], 0, 0, 0);
        }
    }

    // ---- epilogue: scale by 1/l, fp32 stores ----
    #pragma unroll
    for (int nt = 0; nt < 4; ++nt) {
        #pragma unroll
        for (int r = 0; r < 4; ++r) {
            int qrow = s0 + rb*16 + g*4 + r;
            out[((size_t)(b * S_LEN) + qrow) * DH + cc*64 + nt*16 + i] = oacc[nt][r] * linv[r];
        }
    }
}

extern "C" void kernel_launch(void* const* d_in, const int* in_sizes, int n_in,
                              void* d_out, int out_size, void* d_ws, size_t ws_size,
                              hipStream_t stream) {
    const float* x  = (const float*)d_in[0];
    const float* Wq = (const float*)d_in[1];
    const float* bq = (const float*)d_in[2];
    const float* Wk = (const float*)d_in[3];
    const float* bk = (const float*)d_in[4];
    const float* Wv = (const float*)d_in[5];
    const float* bv = (const float*)d_in[6];
    const int* wsz  = (const int*)d_in[7];

    const int B = 2, S = 4096;
    const int N = B * S;                       // 8192 rows

    __hip_bfloat16* q = (__hip_bfloat16*)d_ws;
    __hip_bfloat16* k = q + (size_t)N * DH;
    __hip_bfloat16* v = k + (size_t)N * DH;

    qkv_kernel<<<N / 16, 256, 0, stream>>>(x, Wq, bq, Wk, bk, Wv, bv, q, k, v);
    attn_kernel<<<N / TQ, 256, 0, stream>>>(q, k, v, (float*)d_out, wsz);
}

// Round 3
// 99.837 us; speedup vs baseline: 1.8344x; 1.0058x over previous
//
#include <hip/hip_runtime.h>
#include <hip/hip_bf16.h>

typedef __attribute__((ext_vector_type(8))) short short8;
typedef __attribute__((ext_vector_type(4))) float f32x4;

union U16x8 { uint4 u; short8 s; unsigned short us[8]; };

#define S_LEN 4096
#define DH    128
#define TQ    16          // queries per attn block
#define KEYS  160         // staged key window (144 valid + pad), 10 tiles of 16
#define VTS   168         // V^T LDS row stride in u16 (21 groups of 8, 336B rows)
#define PST   168         // P LDS row stride in u16

// ---------------- Kernel 1: QKV projection, fp32 math, bf16 output ----------
__global__ __launch_bounds__(256) void qkv_kernel(
    const float* __restrict__ x,
    const float* __restrict__ Wq, const float* __restrict__ bq,
    const float* __restrict__ Wk, const float* __restrict__ bk,
    const float* __restrict__ Wv, const float* __restrict__ bv,
    __hip_bfloat16* __restrict__ q, __hip_bfloat16* __restrict__ k,
    __hip_bfloat16* __restrict__ v)
{
    const int t = threadIdx.x;
    const int j = t & 127;
    const int g = t >> 7;            // 0/1 -> rows 8g..8g+7
    const int row0 = blockIdx.x * 16;

    __shared__ float xs[16][DH];
    for (int c = t; c < 512; c += 256) {           // 16*128 floats = 512 float4
        int r = c >> 5, f = c & 31;
        ((float4*)xs[r])[f] = ((const float4*)(x + (size_t)(row0 + r) * DH))[f];
    }
    __syncthreads();

    float aq[8], ak[8], av[8];
    const float bqv = bq[j], bkv = bk[j], bvv = bv[j];
    #pragma unroll
    for (int r = 0; r < 8; ++r) { aq[r] = bqv; ak[r] = bkv; av[r] = bvv; }

    #pragma unroll 2
    for (int d4 = 0; d4 < 32; ++d4) {
        float4 xv[8];
        #pragma unroll
        for (int r = 0; r < 8; ++r) xv[r] = *(const float4*)&xs[g*8 + r][d4*4];
        #pragma unroll
        for (int dd = 0; dd < 4; ++dd) {
            int d = d4*4 + dd;
            float wq = Wq[d*DH + j], wk = Wk[d*DH + j], wv = Wv[d*DH + j];
            #pragma unroll
            for (int r = 0; r < 8; ++r) {
                float xvs = (&xv[r].x)[dd];
                aq[r] = fmaf(xvs, wq, aq[r]);
                ak[r] = fmaf(xvs, wk, ak[r]);
                av[r] = fmaf(xvs, wv, av[r]);
            }
        }
    }
    #pragma unroll
    for (int r = 0; r < 8; ++r) {
        size_t o = (size_t)(row0 + g*8 + r) * DH + j;
        q[o] = __float2bfloat16(aq[r]);
        k[o] = __float2bfloat16(ak[r]);
        v[o] = __float2bfloat16(av[r]);
    }
}

// ---- 8x8 u16 in-register transpose (32 v_perm) + swizzled VT write --------
__device__ inline void vt_xpose_write(unsigned short* VT, const uint4* vr,
                                      int kgp, int dgp)
{
    unsigned w[8][4];   // w[dim][key-pair]
    #pragma unroll
    for (int p = 0; p < 4; ++p) {
        #pragma unroll
        for (int j = 0; j < 4; ++j) {
            unsigned xlo = ((const unsigned*)&vr[2*p])[j];     // key 2p,  dims 2j,2j+1
            unsigned ylo = ((const unsigned*)&vr[2*p+1])[j];   // key 2p+1
            w[2*j][p]   = __builtin_amdgcn_perm(ylo, xlo, 0x05040100u);
            w[2*j+1][p] = __builtin_amdgcn_perm(ylo, xlo, 0x07060302u);
        }
    }
    int sw = kgp + (dgp & 7); if (sw >= 21) sw -= 21;   // bank swizzle, rotate mod 21
    #pragma unroll
    for (int d = 0; d < 8; ++d) {
        int row = dgp*8 + d;
        *(uint4*)&VT[row*VTS + sw*8] =
            make_uint4(w[d][0], w[d][1], w[d][2], w[d][3]);
    }
}

// ---------------- Kernel 2: MFMA sliding-window attention -------------------
// Block = 4 waves, 16 queries, 160-key staged window. Phase A: waves own key
// tiles {w, w+4, w+8}, B-frags gathered straight from global K (cached).
// V transposed into LDS via register 8x8 transpose. Phase B: waves own
// 32-dim strips, P & V^T frags are ds_read_b128.
__global__ __launch_bounds__(256) void attn_kernel(
    const __hip_bfloat16* __restrict__ qg,
    const __hip_bfloat16* __restrict__ kg,
    const __hip_bfloat16* __restrict__ vg,
    float* __restrict__ out, const int* __restrict__ wsz)
{
    __shared__ __align__(16) unsigned short VT[128 * VTS];   // 43 KB
    __shared__ __align__(16) unsigned short Pm[TQ * PST];    // 5.25 KB
    __shared__ float pmax[4][16];
    __shared__ float psum[4][16];

    const int t    = threadIdx.x;
    const int wave = t >> 6, lane = t & 63;
    const int i = lane & 15, g = lane >> 4;
    const int qblk = blockIdx.x;            // 0..511
    const int b    = qblk >> 8;
    const int s0   = (qblk & 255) * TQ;
    const int k0   = s0 - 64;
    const int half = wsz[0] >> 1;
    const float scale = 0.08838834764831845f;

    const __hip_bfloat16* kb = kg + (size_t)b * S_LEN * DH;
    const __hip_bfloat16* vb = vg + (size_t)b * S_LEN * DH;

    // ---- V tile loads (issued first; 8 keys x 8 dims per tile) ----
    const int kgp0 = t >> 4, dgp0 = t & 15;          // tile t
    const bool two = (t & 3) == 0;
    const int tau2 = 256 + (t >> 2);                 // tiles 256..319
    const int kgp1 = tau2 >> 4, dgp1 = tau2 & 15;
    uint4 vr0[8], vr1[8];
    #pragma unroll
    for (int r = 0; r < 8; ++r) {
        int key = k0 + kgp0*8 + r;
        uint4 val = make_uint4(0u,0u,0u,0u);
        if (key >= 0 && key < S_LEN)
            val = *(const uint4*)(vb + (size_t)key * DH + dgp0*8);
        vr0[r] = val;
    }
    #pragma unroll
    for (int r = 0; r < 8; ++r) {
        int key = k0 + kgp1*8 + r;
        uint4 val = make_uint4(0u,0u,0u,0u);
        if (two && key >= 0 && key < S_LEN)
            val = *(const uint4*)(vb + (size_t)key * DH + dgp1*8);
        vr1[r] = val;
    }

    // ---- Q A-frags from global (same rows for all 4 waves -> L1 broadcast) ----
    short8 aq[4];
    {
        const __hip_bfloat16* qrow = qg + (size_t)(b * S_LEN + s0 + i) * DH;
        #pragma unroll
        for (int kc = 0; kc < 4; ++kc) {
            U16x8 u; u.u = *(const uint4*)(qrow + kc*32 + g*8);
            aq[kc] = u.s;
        }
    }

    // ---- Phase A: scores for owned key tiles, B-frags straight from global ----
    const int nkt = (wave < 2) ? 3 : 2;
    f32x4 acc[3];
    #pragma unroll
    for (int u = 0; u < 3; ++u) { acc[u][0]=0.f; acc[u][1]=0.f; acc[u][2]=0.f; acc[u][3]=0.f; }
    #pragma unroll
    for (int u = 0; u < 3; ++u) {
        if (u < nkt) {
            int kt = wave + 4*u;
            int key = k0 + kt*16 + i;               // may be OOB: garbage -> masked
            const __hip_bfloat16* krow = kb + (ptrdiff_t)key * DH;
            #pragma unroll
            for (int kc = 0; kc < 4; ++kc) {
                U16x8 u16v; u16v.u = *(const uint4*)(krow + kc*32 + g*8);
                acc[u] = __builtin_amdgcn_mfma_f32_16x16x32_bf16(aq[kc], u16v.s, acc[u], 0, 0, 0);
            }
        }
    }

    // ---- V transpose + LDS writes (loads have had time to land) ----
    vt_xpose_write(VT, vr0, kgp0, dgp0);
    if (two) vt_xpose_write(VT, vr1, kgp1, dgp1);

    // ---- mask + per-wave row max (C layout: col=i=key, row=g*4+r=query) ----
    float sc[3][4], m4[4];
    #pragma unroll
    for (int r = 0; r < 4; ++r) m4[r] = -3e30f;
    #pragma unroll
    for (int u = 0; u < 3; ++u) {
        if (u < nkt) {
            int kt = wave + 4*u;
            int key = k0 + kt*16 + i;
            #pragma unroll
            for (int r = 0; r < 4; ++r) {
                int qrow = s0 + g*4 + r;
                bool valid = (key >= 0) && (key < S_LEN) &&
                             (key >= qrow - half) && (key <= qrow + half);
                float sv = valid ? acc[u][r] * scale : -1e30f;
                sc[u][r] = sv;
                m4[r] = fmaxf(m4[r], sv);
            }
        }
    }
    #pragma unroll
    for (int r = 0; r < 4; ++r) {
        #pragma unroll
        for (int m = 1; m < 16; m <<= 1)
            m4[r] = fmaxf(m4[r], __shfl_xor(m4[r], m, 64));
    }
    if (i == 0) {
        #pragma unroll
        for (int r = 0; r < 4; ++r) pmax[wave][g*4 + r] = m4[r];
    }
    __syncthreads();   // barrier 1: pmax + VT visible

    // ---- softmax: combine max, exp, write P (bf16), partial sums ----
    float M[4], l4[4];
    #pragma unroll
    for (int r = 0; r < 4; ++r) {
        int qr = g*4 + r;
        M[r] = fmaxf(fmaxf(pmax[0][qr], pmax[1][qr]), fmaxf(pmax[2][qr], pmax[3][qr]));
        l4[r] = 0.f;
    }
    #pragma unroll
    for (int u = 0; u < 3; ++u) {
        if (u < nkt) {
            int kt = wave + 4*u;
            #pragma unroll
            for (int r = 0; r < 4; ++r) {
                float p = __expf(sc[u][r] - M[r]);
                l4[r] += p;
                __hip_bfloat16 pb = __float2bfloat16(p);
                Pm[(g*4 + r) * PST + kt*16 + i] = *(unsigned short*)&pb;
            }
        }
    }
    #pragma unroll
    for (int r = 0; r < 4; ++r) {
        #pragma unroll
        for (int m = 1; m < 16; m <<= 1)
            l4[r] += __shfl_xor(l4[r], m, 64);
    }
    if (i == 0) {
        #pragma unroll
        for (int r = 0; r < 4; ++r) psum[wave][g*4 + r] = l4[r];
    }
    __syncthreads();   // barrier 2: P + psum visible

    // ---- Phase B: O = P V for this wave's 32-dim strip ----
    float linv[4];
    #pragma unroll
    for (int r = 0; r < 4; ++r) {
        int qr = g*4 + r;
        linv[r] = 1.0f / (psum[0][qr] + psum[1][qr] + psum[2][qr] + psum[3][qr]);
    }

    short8 ap[5];
    #pragma unroll
    for (int kc = 0; kc < 5; ++kc)
        ap[kc] = *(const short8*)&Pm[i * PST + kc*32 + g*8];

    const int n0 = wave * 32;
    f32x4 oacc[2];
    #pragma unroll
    for (int nt = 0; nt < 2; ++nt) { oacc[nt][0]=0.f; oacc[nt][1]=0.f; oacc[nt][2]=0.f; oacc[nt][3]=0.f; }
    #pragma unroll
    for (int nt = 0; nt < 2; ++nt) {
        int row0 = n0 + nt*16 + i;                 // V^T row = dim
        int dgr = (row0 >> 3) & 7;
        #pragma unroll
        for (int kc = 0; kc < 5; ++kc) {
            int lg = 4*kc + g;
            int sw = lg + dgr; if (sw >= 21) sw -= 21;
            short8 bv = *(const short8*)&VT[row0 * VTS + sw*8];
            oacc[nt] = __builtin_amdgcn_mfma_f32_16x16x32_bf16(ap[kc], bv, oacc[nt], 0, 0, 0);
        }
    }

    // ---- epilogue ----
    #pragma unroll
    for (int nt = 0; nt < 2; ++nt) {
        #pragma unroll
        for (int r = 0; r < 4; ++r) {
            int qrow = s0 + g*4 + r;
            out[((size_t)(b * S_LEN) + qrow) * DH + n0 + nt*16 + i] = oacc[nt][r] * linv[r];
        }
    }
}

extern "C" void kernel_launch(void* const* d_in, const int* in_sizes, int n_in,
                              void* d_out, int out_size, void* d_ws, size_t ws_size,
                              hipStream_t stream) {
    const float* x  = (const float*)d_in[0];
    const float* Wq = (const float*)d_in[1];
    const float* bq = (const float*)d_in[2];
    const float* Wk = (const float*)d_in[3];
    const float* bk = (const float*)d_in[4];
    const float* Wv = (const float*)d_in[5];
    const float* bv = (const float*)d_in[6];
    const int* wsz  = (const int*)d_in[7];

    const int B = 2, S = 4096;
    const int N = B * S;                       // 8192 rows

    __hip_bfloat16* q = (__hip_bfloat16*)d_ws;
    __hip_bfloat16* k = q + (size_t)N * DH;
    __hip_bfloat16* v = k + (size_t)N * DH;

    qkv_kernel<<<N / 16, 256, 0, stream>>>(x, Wq, bq, Wk, bk, Wv, bv, q, k, v);
    attn_kernel<<<N / TQ, 256, 0, stream>>>(q, k, v, (float*)d_out, wsz);
}

// Round 4
// 95.731 us; speedup vs baseline: 1.9131x; 1.0429x over previous
//
#include <hip/hip_runtime.h>
#include <hip/hip_bf16.h>

typedef __attribute__((ext_vector_type(8))) short short8;
typedef __attribute__((ext_vector_type(4))) float f32x4;

union U16x8 { uint4 u; short8 s; unsigned short us[8]; };

#define S_LEN 4096
#define DH    128
#define TQ    16          // queries per attn block
#define VTS   168         // V^T LDS row stride in u16 (21 groups of 8, 336B rows)
#define PST   168         // P LDS row stride in u16
#define XSTR  136         // x-tile LDS stride (bf16 elems)

// ---------------- Kernel 1: QKV projection via MFMA ------------------------
// x split hi/lo bf16 (2-term MFMA -> fp32-quality x), W single bf16.
// Block = 256 thr / 4 waves, 32 rows. Wave owns a 32-col strip for all 3 mats.
__global__ __launch_bounds__(256) void qkv_kernel(
    const float* __restrict__ x,
    const float* __restrict__ Wq, const float* __restrict__ bq,
    const float* __restrict__ Wk, const float* __restrict__ bk,
    const float* __restrict__ Wv, const float* __restrict__ bv,
    __hip_bfloat16* __restrict__ q, __hip_bfloat16* __restrict__ k,
    __hip_bfloat16* __restrict__ v)
{
    __shared__ __align__(16) unsigned short XH[32 * XSTR];
    __shared__ __align__(16) unsigned short XL[32 * XSTR];

    const int t = threadIdx.x;
    const int row0 = blockIdx.x * 32;

    // ---- stage x as hi/lo bf16 ----
    #pragma unroll
    for (int p = 0; p < 4; ++p) {
        int c = t + p * 256;                 // 0..1023
        int r = c >> 5, cg = c & 31;         // row, float4 group
        float4 xv = *(const float4*)(x + (size_t)(row0 + r) * DH + cg * 4);
        unsigned h[2], l[2];
        #pragma unroll
        for (int hw = 0; hw < 2; ++hw) {
            unsigned hh[2], ll[2];
            #pragma unroll
            for (int j = 0; j < 2; ++j) {
                float xs = (&xv.x)[hw * 2 + j];
                __hip_bfloat16 hb = __float2bfloat16(xs);
                float hf = __bfloat162float(hb);
                __hip_bfloat16 lb = __float2bfloat16(xs - hf);
                hh[j] = *(unsigned short*)&hb;
                ll[j] = *(unsigned short*)&lb;
            }
            h[hw] = hh[0] | (hh[1] << 16);
            l[hw] = ll[0] | (ll[1] << 16);
        }
        *(uint2*)&XH[r * XSTR + cg * 4] = make_uint2(h[0], h[1]);
        *(uint2*)&XL[r * XSTR + cg * 4] = make_uint2(l[0], l[1]);
    }
    __syncthreads();

    const int wave = t >> 6, lane = t & 63;
    const int i = lane & 15, g = lane >> 4;

    // ---- A fragments (row m = i, k = kc*32 + g*8 + j) ----
    short8 ah[2][4], al[2][4];
    #pragma unroll
    for (int rt = 0; rt < 2; ++rt)
        #pragma unroll
        for (int kc = 0; kc < 4; ++kc) {
            ah[rt][kc] = *(const short8*)&XH[(rt*16 + i) * XSTR + kc*32 + g*8];
            al[rt][kc] = *(const short8*)&XL[(rt*16 + i) * XSTR + kc*32 + g*8];
        }

    const float* Ws[3] = {Wq, Wk, Wv};
    const float* Bs[3] = {bq, bk, bv};
    __hip_bfloat16* Os[3] = {q, k, v};

    #pragma unroll
    for (int mat = 0; mat < 3; ++mat) {
        #pragma unroll
        for (int ct = 0; ct < 2; ++ct) {
            const int col = wave*32 + ct*16 + i;
            const float bias = Bs[mat][col];

            // B frags: col n = i, k = kc*32 + g*8 + j  (strided gather from W)
            short8 bf[4];
            #pragma unroll
            for (int kc = 0; kc < 4; ++kc) {
                const float* wp = Ws[mat] + (size_t)(kc*32 + g*8) * DH + col;
                U16x8 u;
                #pragma unroll
                for (int j = 0; j < 8; ++j) {
                    __hip_bfloat16 wb = __float2bfloat16(wp[(size_t)j * DH]);
                    u.us[j] = *(unsigned short*)&wb;
                }
                bf[kc] = u.s;
            }

            #pragma unroll
            for (int rt = 0; rt < 2; ++rt) {
                f32x4 acc; acc[0]=0.f; acc[1]=0.f; acc[2]=0.f; acc[3]=0.f;
                #pragma unroll
                for (int kc = 0; kc < 4; ++kc) {
                    acc = __builtin_amdgcn_mfma_f32_16x16x32_bf16(ah[rt][kc], bf[kc], acc, 0, 0, 0);
                    acc = __builtin_amdgcn_mfma_f32_16x16x32_bf16(al[rt][kc], bf[kc], acc, 0, 0, 0);
                }
                #pragma unroll
                for (int r = 0; r < 4; ++r) {
                    Os[mat][(size_t)(row0 + rt*16 + g*4 + r) * DH + col] =
                        __float2bfloat16(acc[r] + bias);
                }
            }
        }
    }
}

// ---- 8x8 u16 in-register transpose (32 v_perm) + swizzled VT write --------
__device__ inline void vt_xpose_write(unsigned short* VT, const uint4* vr,
                                      int kgp, int dgp)
{
    unsigned w[8][4];   // w[dim][key-pair]
    #pragma unroll
    for (int p = 0; p < 4; ++p) {
        #pragma unroll
        for (int j = 0; j < 4; ++j) {
            unsigned xlo = ((const unsigned*)&vr[2*p])[j];     // key 2p,  dims 2j,2j+1
            unsigned ylo = ((const unsigned*)&vr[2*p+1])[j];   // key 2p+1
            w[2*j][p]   = __builtin_amdgcn_perm(ylo, xlo, 0x05040100u);
            w[2*j+1][p] = __builtin_amdgcn_perm(ylo, xlo, 0x07060302u);
        }
    }
    int sw = kgp + (dgp & 7); if (sw >= 21) sw -= 21;   // bank swizzle, rotate mod 21
    #pragma unroll
    for (int d = 0; d < 8; ++d) {
        int row = dgp*8 + d;
        *(uint4*)&VT[row*VTS + sw*8] =
            make_uint4(w[d][0], w[d][1], w[d][2], w[d][3]);
    }
}

// ---------------- Kernel 2: MFMA sliding-window attention -------------------
// Block = 4 waves, 16 queries, 160-key staged window. Phase A: waves own key
// tiles {w, w+4, w+8}, B-frags gathered straight from global K (cached).
// V transposed into LDS via register 8x8 transpose. Phase B: waves own
// 32-dim strips, P & V^T frags are ds_read_b128.
__global__ __launch_bounds__(256) void attn_kernel(
    const __hip_bfloat16* __restrict__ qg,
    const __hip_bfloat16* __restrict__ kg,
    const __hip_bfloat16* __restrict__ vg,
    float* __restrict__ out, const int* __restrict__ wsz)
{
    __shared__ __align__(16) unsigned short VT[128 * VTS];   // 43 KB
    __shared__ __align__(16) unsigned short Pm[TQ * PST];    // 5.25 KB
    __shared__ float pmax[4][16];
    __shared__ float psum[4][16];

    const int t    = threadIdx.x;
    const int wave = t >> 6, lane = t & 63;
    const int i = lane & 15, g = lane >> 4;
    const int qblk = blockIdx.x;            // 0..511
    const int b    = qblk >> 8;
    const int s0   = (qblk & 255) * TQ;
    const int k0   = s0 - 64;
    const int half = wsz[0] >> 1;
    const float scale = 0.08838834764831845f;

    const __hip_bfloat16* kb = kg + (size_t)b * S_LEN * DH;
    const __hip_bfloat16* vb = vg + (size_t)b * S_LEN * DH;

    // ---- V tile loads (issued first; 8 keys x 8 dims per tile) ----
    const int kgp0 = t >> 4, dgp0 = t & 15;          // tile t
    const bool two = (t & 3) == 0;
    const int tau2 = 256 + (t >> 2);                 // tiles 256..319
    const int kgp1 = tau2 >> 4, dgp1 = tau2 & 15;
    uint4 vr0[8], vr1[8];
    #pragma unroll
    for (int r = 0; r < 8; ++r) {
        int key = k0 + kgp0*8 + r;
        uint4 val = make_uint4(0u,0u,0u,0u);
        if (key >= 0 && key < S_LEN)
            val = *(const uint4*)(vb + (size_t)key * DH + dgp0*8);
        vr0[r] = val;
    }
    #pragma unroll
    for (int r = 0; r < 8; ++r) {
        int key = k0 + kgp1*8 + r;
        uint4 val = make_uint4(0u,0u,0u,0u);
        if (two && key >= 0 && key < S_LEN)
            val = *(const uint4*)(vb + (size_t)key * DH + dgp1*8);
        vr1[r] = val;
    }

    // ---- Q A-frags from global (same rows for all 4 waves -> L1 broadcast) ----
    short8 aq[4];
    {
        const __hip_bfloat16* qrow = qg + (size_t)(b * S_LEN + s0 + i) * DH;
        #pragma unroll
        for (int kc = 0; kc < 4; ++kc) {
            U16x8 u; u.u = *(const uint4*)(qrow + kc*32 + g*8);
            aq[kc] = u.s;
        }
    }

    // ---- Phase A: scores for owned key tiles, B-frags straight from global ----
    const int nkt = (wave < 2) ? 3 : 2;
    f32x4 acc[3];
    #pragma unroll
    for (int u = 0; u < 3; ++u) { acc[u][0]=0.f; acc[u][1]=0.f; acc[u][2]=0.f; acc[u][3]=0.f; }
    #pragma unroll
    for (int u = 0; u < 3; ++u) {
        if (u < nkt) {
            int kt = wave + 4*u;
            int key = k0 + kt*16 + i;               // may be OOB: garbage -> masked
            const __hip_bfloat16* krow = kb + (ptrdiff_t)key * DH;
            #pragma unroll
            for (int kc = 0; kc < 4; ++kc) {
                U16x8 u16v; u16v.u = *(const uint4*)(krow + kc*32 + g*8);
                acc[u] = __builtin_amdgcn_mfma_f32_16x16x32_bf16(aq[kc], u16v.s, acc[u], 0, 0, 0);
            }
        }
    }

    // ---- V transpose + LDS writes (loads have had time to land) ----
    vt_xpose_write(VT, vr0, kgp0, dgp0);
    if (two) vt_xpose_write(VT, vr1, kgp1, dgp1);

    // ---- mask + per-wave row max (C layout: col=i=key, row=g*4+r=query) ----
    float sc[3][4], m4[4];
    #pragma unroll
    for (int r = 0; r < 4; ++r) m4[r] = -3e30f;
    #pragma unroll
    for (int u = 0; u < 3; ++u) {
        if (u < nkt) {
            int kt = wave + 4*u;
            int key = k0 + kt*16 + i;
            #pragma unroll
            for (int r = 0; r < 4; ++r) {
                int qrow = s0 + g*4 + r;
                bool valid = (key >= 0) && (key < S_LEN) &&
                             (key >= qrow - half) && (key <= qrow + half);
                float sv = valid ? acc[u][r] * scale : -1e30f;
                sc[u][r] = sv;
                m4[r] = fmaxf(m4[r], sv);
            }
        }
    }
    #pragma unroll
    for (int r = 0; r < 4; ++r) {
        #pragma unroll
        for (int m = 1; m < 16; m <<= 1)
            m4[r] = fmaxf(m4[r], __shfl_xor(m4[r], m, 64));
    }
    if (i == 0) {
        #pragma unroll
        for (int r = 0; r < 4; ++r) pmax[wave][g*4 + r] = m4[r];
    }
    __syncthreads();   // barrier 1: pmax + VT visible

    // ---- softmax: combine max, exp, write P (bf16), partial sums ----
    float M[4], l4[4];
    #pragma unroll
    for (int r = 0; r < 4; ++r) {
        int qr = g*4 + r;
        M[r] = fmaxf(fmaxf(pmax[0][qr], pmax[1][qr]), fmaxf(pmax[2][qr], pmax[3][qr]));
        l4[r] = 0.f;
    }
    #pragma unroll
    for (int u = 0; u < 3; ++u) {
        if (u < nkt) {
            int kt = wave + 4*u;
            #pragma unroll
            for (int r = 0; r < 4; ++r) {
                float p = __expf(sc[u][r] - M[r]);
                l4[r] += p;
                __hip_bfloat16 pb = __float2bfloat16(p);
                Pm[(g*4 + r) * PST + kt*16 + i] = *(unsigned short*)&pb;
            }
        }
    }
    #pragma unroll
    for (int r = 0; r < 4; ++r) {
        #pragma unroll
        for (int m = 1; m < 16; m <<= 1)
            l4[r] += __shfl_xor(l4[r], m, 64);
    }
    if (i == 0) {
        #pragma unroll
        for (int r = 0; r < 4; ++r) psum[wave][g*4 + r] = l4[r];
    }
    __syncthreads();   // barrier 2: P + psum visible

    // ---- Phase B: O = P V for this wave's 32-dim strip ----
    float linv[4];
    #pragma unroll
    for (int r = 0; r < 4; ++r) {
        int qr = g*4 + r;
        linv[r] = 1.0f / (psum[0][qr] + psum[1][qr] + psum[2][qr] + psum[3][qr]);
    }

    short8 ap[5];
    #pragma unroll
    for (int kc = 0; kc < 5; ++kc)
        ap[kc] = *(const short8*)&Pm[i * PST + kc*32 + g*8];

    const int n0 = wave * 32;
    f32x4 oacc[2];
    #pragma unroll
    for (int nt = 0; nt < 2; ++nt) { oacc[nt][0]=0.f; oacc[nt][1]=0.f; oacc[nt][2]=0.f; oacc[nt][3]=0.f; }
    #pragma unroll
    for (int nt = 0; nt < 2; ++nt) {
        int row0 = n0 + nt*16 + i;                 // V^T row = dim
        int dgr = (row0 >> 3) & 7;
        #pragma unroll
        for (int kc = 0; kc < 5; ++kc) {
            int lg = 4*kc + g;
            int sw = lg + dgr; if (sw >= 21) sw -= 21;
            short8 bv = *(const short8*)&VT[row0 * VTS + sw*8];
            oacc[nt] = __builtin_amdgcn_mfma_f32_16x16x32_bf16(ap[kc], bv, oacc[nt], 0, 0, 0);
        }
    }

    // ---- epilogue ----
    #pragma unroll
    for (int nt = 0; nt < 2; ++nt) {
        #pragma unroll
        for (int r = 0; r < 4; ++r) {
            int qrow = s0 + g*4 + r;
            out[((size_t)(b * S_LEN) + qrow) * DH + n0 + nt*16 + i] = oacc[nt][r] * linv[r];
        }
    }
}

extern "C" void kernel_launch(void* const* d_in, const int* in_sizes, int n_in,
                              void* d_out, int out_size, void* d_ws, size_t ws_size,
                              hipStream_t stream) {
    const float* x  = (const float*)d_in[0];
    const float* Wq = (const float*)d_in[1];
    const float* bq = (const float*)d_in[2];
    const float* Wk = (const float*)d_in[3];
    const float* bk = (const float*)d_in[4];
    const float* Wv = (const float*)d_in[5];
    const float* bv = (const float*)d_in[6];
    const int* wsz  = (const int*)d_in[7];

    const int B = 2, S = 4096;
    const int N = B * S;                       // 8192 rows

    __hip_bfloat16* q = (__hip_bfloat16*)d_ws;
    __hip_bfloat16* k = q + (size_t)N * DH;
    __hip_bfloat16* v = k + (size_t)N * DH;

    qkv_kernel<<<N / 32, 256, 0, stream>>>(x, Wq, bq, Wk, bk, Wv, bv, q, k, v);
    attn_kernel<<<N / TQ, 256, 0, stream>>>(q, k, v, (float*)d_out, wsz);
}